// Round 1
// baseline (790.389 us; speedup 1.0000x reference)
//
#include <hip/hip_runtime.h>

typedef __attribute__((ext_vector_type(4))) float f32x4;
typedef __attribute__((ext_vector_type(4))) int   i32x4;
typedef __attribute__((ext_vector_type(8))) short s16x8;

#define NB 32
#define NS 8192
#define ND 512
#define NM 16

// pack two fp32 into one u32 of 2 bf16 (truncation; lo-term corrects the error)
__device__ __forceinline__ unsigned bfpack(float e1, float e0) {
  return __builtin_amdgcn_perm(__builtin_bit_cast(unsigned, e1),
                               __builtin_bit_cast(unsigned, e0), 0x07060302u);
}
__device__ __forceinline__ float hitrunc(float v) {
  unsigned u = __builtin_bit_cast(unsigned, v) & 0xffff0000u;
  return __builtin_bit_cast(float, u);
}
// split 8 fp32 (xa,xb) into hi/lo bf16 MFMA fragments
__device__ __forceinline__ void split8(const f32x4 xa, const f32x4 xb,
                                       s16x8 &hi, s16x8 &lo) {
  i32x4 h, l;
  h[0] = (int)bfpack(xa[1], xa[0]);
  h[1] = (int)bfpack(xa[3], xa[2]);
  h[2] = (int)bfpack(xb[1], xb[0]);
  h[3] = (int)bfpack(xb[3], xb[2]);
  float l0 = xa[0] - hitrunc(xa[0]), l1 = xa[1] - hitrunc(xa[1]);
  float l2 = xa[2] - hitrunc(xa[2]), l3 = xa[3] - hitrunc(xa[3]);
  float l4 = xb[0] - hitrunc(xb[0]), l5 = xb[1] - hitrunc(xb[1]);
  float l6 = xb[2] - hitrunc(xb[2]), l7 = xb[3] - hitrunc(xb[3]);
  l[0] = (int)bfpack(l1, l0);
  l[1] = (int)bfpack(l3, l2);
  l[2] = (int)bfpack(l5, l4);
  l[3] = (int)bfpack(l7, l6);
  hi = __builtin_bit_cast(s16x8, h);
  lo = __builtin_bit_cast(s16x8, l);
}

// Kernel 1: per (b, chunk) block. Phase A: scores via split-bf16 MFMA.
// Phase B: online-softmax pooled accumulation (fp32 VALU), x re-read from L1/L2.
__global__ __launch_bounds__(256) void pool_chunk_kernel(
    const float* __restrict__ x, const float* __restrict__ seeds,
    float* __restrict__ Po, float* __restrict__ Pml, int C, int R)
{
  __shared__ s16x8 sh_seed_hi[16 * 64];
  __shared__ s16x8 sh_seed_lo[16 * 64];
  __shared__ __align__(16) float sh_w[64][20];   // weights for 64-row group, padded
  __shared__ float sh_gmax[4][16];
  __shared__ float sh_rmax[16];
  __shared__ float sh_rfac[16];

  const int tid = threadIdx.x;
  const int wv = tid >> 6, lane = tid & 63;
  const int b = blockIdx.y, chunk = blockIdx.x;

  // stage seeds hi/lo fragments: task (kt 0..15, l 0..63)
  for (int rep = 0; rep < 4; ++rep) {
    int idx = tid + rep * 256;
    int l = idx & 63, kt = idx >> 6;
    int m = l & 15, dbase = kt * 32 + (l >> 4) * 8;
    const f32x4* sp = (const f32x4*)(seeds + m * ND + dbase);
    f32x4 sa = sp[0], sb = sp[1];
    s16x8 h, lo_;
    split8(sa, sb, h, lo_);
    sh_seed_hi[idx] = h;
    sh_seed_lo[idx] = lo_;
  }
  if (tid < 16) sh_rmax[tid] = -__builtin_inff();
  __syncthreads();

  const int lr = lane & 15;       // phase-A: row-within-16-group
  const int kq = lane >> 4;       // phase-A: k-octet group
  const int mi0 = kq * 4;         // phase-A: m base in C-frag
  const int mh = wv >> 1, dh = wv & 1;   // phase-B: m-half / d-half
  const int mb = mh * 8;
  const int db = dh * 256 + lane * 4;

  f32x4 acc[8];
  float lacc[8];
  #pragma unroll
  for (int j = 0; j < 8; ++j) { acc[j] = f32x4{0.f, 0.f, 0.f, 0.f}; lacc[j] = 0.f; }

  const int groups = R >> 6;
  for (int g = 0; g < groups; ++g) {
    // pre-read running max (stable: written only after next barrier)
    float rm_old[4];
    #pragma unroll
    for (int r = 0; r < 4; ++r) rm_old[r] = sh_rmax[mi0 + r];
    float rm_t = (tid < 16) ? sh_rmax[tid] : 0.f;

    // ---- phase A: scores[16m][16rows] for this wave's rows
    const int row = chunk * R + g * 64 + wv * 16 + lr;
    const f32x4* xrow = (const f32x4*)(x + ((size_t)b * NS + row) * ND);
    f32x4 Cv = f32x4{0.f, 0.f, 0.f, 0.f};
    #pragma unroll
    for (int kt = 0; kt < 16; ++kt) {
      f32x4 xa = xrow[kt * 8 + kq * 2];
      f32x4 xb = xrow[kt * 8 + kq * 2 + 1];
      s16x8 bh, bl;
      split8(xa, xb, bh, bl);
      s16x8 ah = sh_seed_hi[kt * 64 + lane];
      s16x8 al = sh_seed_lo[kt * 64 + lane];
      Cv = __builtin_amdgcn_mfma_f32_16x16x32_bf16(ah, bh, Cv, 0, 0, 0);
      Cv = __builtin_amdgcn_mfma_f32_16x16x32_bf16(ah, bl, Cv, 0, 0, 0);
      Cv = __builtin_amdgcn_mfma_f32_16x16x32_bf16(al, bh, Cv, 0, 0, 0);
    }
    // per-m max over this wave's 16 rows (reduce over lane bits 0..3)
    float vmax[4];
    #pragma unroll
    for (int r = 0; r < 4; ++r) {
      float v = Cv[r];
      v = fmaxf(v, __shfl_xor(v, 1, 64));
      v = fmaxf(v, __shfl_xor(v, 2, 64));
      v = fmaxf(v, __shfl_xor(v, 4, 64));
      v = fmaxf(v, __shfl_xor(v, 8, 64));
      vmax[r] = v;
    }
    if (lr == 0) {
      #pragma unroll
      for (int r = 0; r < 4; ++r) sh_gmax[wv][mi0 + r] = vmax[r];
    }
    __syncthreads();
    // ---- weights with block-wide running max
    #pragma unroll
    for (int r = 0; r < 4; ++r) {
      float Mv = rm_old[r];
      Mv = fmaxf(Mv, sh_gmax[0][mi0 + r]);
      Mv = fmaxf(Mv, sh_gmax[1][mi0 + r]);
      Mv = fmaxf(Mv, sh_gmax[2][mi0 + r]);
      Mv = fmaxf(Mv, sh_gmax[3][mi0 + r]);
      sh_w[wv * 16 + lr][mi0 + r] = __expf(Cv[r] - Mv);
    }
    if (tid < 16) {
      float Mv = rm_t;
      Mv = fmaxf(Mv, sh_gmax[0][tid]);
      Mv = fmaxf(Mv, sh_gmax[1][tid]);
      Mv = fmaxf(Mv, sh_gmax[2][tid]);
      Mv = fmaxf(Mv, sh_gmax[3][tid]);
      sh_rfac[tid] = __expf(rm_t - Mv);
      sh_rmax[tid] = Mv;
    }
    __syncthreads();
    // ---- phase B: pooled accumulation for (8 m) x (256 d) per wave
    float fj[8];
    #pragma unroll
    for (int j = 0; j < 8; ++j) fj[j] = sh_rfac[mb + j];
    #pragma unroll
    for (int j = 0; j < 8; ++j) { acc[j] *= fj[j]; lacc[j] *= fj[j]; }
    const float* xg = x + ((size_t)b * NS + chunk * R + g * 64) * ND + db;
    #pragma unroll 4
    for (int r = 0; r < 64; ++r) {
      f32x4 xv = *(const f32x4*)(xg + (size_t)r * ND);
      f32x4 w0 = *(const f32x4*)&sh_w[r][mb];
      f32x4 w1 = *(const f32x4*)&sh_w[r][mb + 4];
      #pragma unroll
      for (int j = 0; j < 4; ++j) { acc[j]     += w0[j] * xv; lacc[j]     += w0[j]; }
      #pragma unroll
      for (int j = 0; j < 4; ++j) { acc[4 + j] += w1[j] * xv; lacc[4 + j] += w1[j]; }
    }
  }
  // ---- write partials: Po[b][chunk][m][512], Pml[b][chunk][m][2] = {max, sumexp}
  float* po = Po + (((size_t)b * C + chunk) * NM + mb) * ND + db;
  #pragma unroll
  for (int j = 0; j < 8; ++j) *(f32x4*)(po + (size_t)j * ND) = acc[j];
  if (dh == 0 && lane == 0) {
    float* pm = Pml + (((size_t)b * C + chunk) * NM + mb) * 2;
    #pragma unroll
    for (int j = 0; j < 8; ++j) {
      pm[2 * j]     = sh_rmax[mb + j];
      pm[2 * j + 1] = lacc[j];
    }
  }
}

// Kernel 2: combine C chunk-partials per (b, m)
__global__ __launch_bounds__(64) void combine_kernel(
    const float* __restrict__ Po, const float* __restrict__ Pml,
    float* __restrict__ out, int C)
{
  const int m = blockIdx.x, b = blockIdx.y;
  const int lane = threadIdx.x;
  float Mv = -__builtin_inff();
  for (int c = 0; c < C; ++c)
    Mv = fmaxf(Mv, Pml[(((size_t)b * C + c) * NM + m) * 2]);
  f32x4 a0 = f32x4{0.f, 0.f, 0.f, 0.f};
  f32x4 a1 = f32x4{0.f, 0.f, 0.f, 0.f};
  float L = 0.f;
  for (int c = 0; c < C; ++c) {
    size_t base = ((size_t)b * C + c) * NM + m;
    float mc = Pml[base * 2], lc = Pml[base * 2 + 1];
    float f = __expf(mc - Mv);
    L += lc * f;
    const f32x4* po = (const f32x4*)(Po + base * ND);
    a0 += f * po[lane];
    a1 += f * po[lane + 64];
  }
  float inv = 1.0f / L;
  f32x4* o = (f32x4*)(out + ((size_t)b * NM + m) * ND);
  o[lane]      = a0 * inv;
  o[lane + 64] = a1 * inv;
}

extern "C" void kernel_launch(void* const* d_in, const int* in_sizes, int n_in,
                              void* d_out, int out_size, void* d_ws, size_t ws_size,
                              hipStream_t stream)
{
  const float* x     = (const float*)d_in[0];
  const float* seeds = (const float*)d_in[1];
  float* out = (float*)d_out;

  int C = 32;
  while (C > 1) {
    size_t need = (size_t)NB * C * NM * ND * 4 + (size_t)NB * C * NM * 2 * 4;
    if (need <= ws_size) break;
    C >>= 1;
  }
  int R = NS / C;
  float* Po  = (float*)d_ws;
  float* Pml = Po + (size_t)NB * C * NM * ND;

  dim3 g1(C, NB);
  pool_chunk_kernel<<<g1, dim3(256), 0, stream>>>(x, seeds, Po, Pml, C, R);
  dim3 g2(NM, NB);
  combine_kernel<<<g2, dim3(64), 0, stream>>>(Po, Pml, out, C);
}